// Round 12
// baseline (120.836 us; speedup 1.0000x reference)
//
#include <hip/hip_runtime.h>

// 8 x 512 x 512 f32 -> 17x17 windows @ stride 4 -> 124x124 windows/batch -> (8,68) means.
// R12: TWO kernels (R11 post-mortem: each extra dispatch ~5 us; mask precompute kernel is
// obsolete under fat blocks). Feature kernel = exact R10 structure (verified best: 12-wave
// 768-thr block per 16x8-window tile, 2 vert-adjacent windows/lane via A/S/B phase
// counters, pre-sliced uint4 LDS masks, unroll-1 SEGRUN w/ prefetch) but phase A builds
// the slices DIRECTLY from x via wave ballots (77 rows / 12 waves, coalesced 64-lane row
// loads, 4 cmp + 4 ballots each) — no mg workspace round-trip.
// Off-diag bins: disjoint union -> single popc. Partials to unique d_ws slots (no global
// atomics — R6's 3.5x win); tiny reduce kernel sums 128 partials/(b,ch).
// Wave roles (wid): 0 stats ch0-3 | 1 hist ch4-7 | 2:(0,1)k0 3:(1,0)k2 4:(0,2)k4
//   5:(1,1)k1,k5 6:(0,4)k8 7:(1,-1)k3,k7 8:(2,0)k6 9:(3,3)k9 10:(4,0)k10 11:(3,-3)k11
// ws: float part[8][68][128] (278 KB).

#define G_MEAN_F 85.384f
#define G_STD_F  53.798f

__device__ constexpr int LO15[15] = {0,0,0,0,0,1,1,1,1,2,2,2,3,3,4};
__device__ constexpr int HI15[15] = {0,1,2,3,4,1,2,3,4,2,3,4,3,4,4};

__device__ __forceinline__ float wred(float v) {
#pragma unroll
  for (int m = 32; m; m >>= 1) v += __shfl_xor(v, m, 64);
  return v;
}

// Load pre-sliced levels 1-4 for slice index (row*8+ly); level 0 by complement.
__device__ __forceinline__ void load_sl(const unsigned* sl, int idx, unsigned m[5]) {
  const uint4 q = *(const uint4*)(sl + idx * 4);
  m[1] = q.x; m[2] = q.y; m[3] = q.z; m[4] = q.w;
  m[0] = 0x1FFFFu & ~(m[1] | m[2] | m[3] | m[4]);
}

// cnt[u] += popc over 15 unordered bins; off-diag sets disjoint -> popc of the union.
template<int DC>
__device__ __forceinline__ void updoff(unsigned* cnt, const unsigned a[5], const unsigned b[5]) {
  unsigned as[5], bs[5];
#pragma unroll
  for (int v = 0; v < 5; ++v) {
    as[v] = (DC < 0) ? (a[v] >> (-DC)) : a[v];
    bs[v] = (DC > 0) ? (b[v] >> DC) : b[v];
  }
#pragma unroll
  for (int u = 0; u < 15; ++u) {
    const int i = LO15[u], j = HI15[u];
    unsigned t = as[i] & bs[j];
    if (i != j) t |= as[j] & bs[i];
    cnt[u] += __popc(t);
  }
}

// GLCM features from symmetric-unordered pair counts (math verified R1-R11).
__device__ __forceinline__ void feat5(const unsigned* cnt, float Np,
                                      float& con, float& hom, float& ene,
                                      float& corr, float& ent) {
  const float invN = 1.0f / Np;
  const float inv2N = 0.5f / Np;
  con = 0.0f; hom = 0.0f; ent = 0.0f;
  float eac = 0.0f;
  float P[5] = {0, 0, 0, 0, 0};
#pragma unroll
  for (int u = 0; u < 15; ++u) {
    const int lo = LO15[u], hi = HI15[u];
    const float m = (float)cnt[u];
    const float d2 = (float)((hi - lo) * (hi - lo));
    con += m * d2;
    hom += m * (1.0f / (1.0f + d2));
    if (lo == hi) {
      eac += m * m;
      P[lo] += 2.0f * m;
      float g = m * invN;
      ent -= g * __log2f(g + 1e-8f);
    } else {
      eac += 0.5f * m * m;
      P[lo] += m; P[hi] += m;
      float g = m * inv2N;
      ent -= 2.0f * g * __log2f(g + 1e-8f);
    }
  }
  con *= invN;
  hom *= invN;
  ene = sqrtf(eac) * invN;
  float mu = 0.0f;
#pragma unroll
  for (int i = 0; i < 5; ++i) { P[i] *= inv2N; mu += (float)i * P[i]; }
  float s2 = 0.0f;
#pragma unroll
  for (int i = 0; i < 5; ++i) { float d = (float)i - mu; s2 = fmaf(P[i] * d, d, s2); }
  float denom = s2;
  float cov = 0.0f;
#pragma unroll
  for (int u = 0; u < 15; ++u)
    cov += ((float)cnt[u] * invN) * ((float)LO15[u] - mu) * ((float)HI15[u] - mu);
  corr = (denom < 1e-15f) ? 1.0f : cov / fmaxf(denom, 1e-30f);
}

// Emit both packed windows' features (summed, validity-masked) to unique partial slots.
__device__ __forceinline__ void emit2(const unsigned c1[15], const unsigned c2[15], float Np,
                                      bool v1, bool v2, float* pt0, int k0, int k1) {
  float con1, hom1, ene1, cor1, ent1, con2, hom2, ene2, cor2, ent2;
  feat5(c1, Np, con1, hom1, ene1, cor1, ent1);
  feat5(c2, Np, con2, hom2, ene2, cor2, ent2);
  if (!v1) { con1 = 0; hom1 = 0; ene1 = 0; cor1 = 0; ent1 = 0; }
  if (!v2) { con2 = 0; hom2 = 0; ene2 = 0; cor2 = 0; ent2 = 0; }
  float con = wred(con1 + con2), hom = wred(hom1 + hom2), ene = wred(ene1 + ene2);
  float cor = wred(cor1 + cor2), ent = wred(ent1 + ent2);
  if ((threadIdx.x & 63) == 0) {
    const float s = 1.0f / 15376.0f;
    pt0[(8 + k0) * 128] = con * s;
    pt0[(20 + k0) * 128] = hom * s;
    pt0[(32 + k0) * 128] = ene * s;
    pt0[(44 + k0) * 128] = cor * s;
    pt0[(56 + k0) * 128] = ent * s;
    if (k1 >= 0) {
      pt0[(8 + k1) * 128] = con * s;
      pt0[(20 + k1) * 128] = hom * s;
      pt0[(32 + k1) * 128] = ene * s;
      pt0[(44 + k1) * 128] = cor * s;
      pt0[(56 + k1) * 128] = ent * s;
    }
  }
}

// One offset over 2 vertically-adjacent windows. Phases: A rows R<4 (w1 only),
// S rows [4,17-DR) (shared), B rows [17-DR,21-DR) (w2 only). Each LDS row loaded ONCE;
// next row prefetched before the current row's AND/POPC body (R10-verified, unroll-1).
template<int DR, int DC>
__device__ void glcm2(const unsigned* sl, int s, int ly, bool v1, bool v2,
                      float Np, float* pt0, int k0, int k1) {
  unsigned A[15], S[15], B[15];
#pragma unroll
  for (int u = 0; u < 15; ++u) { A[u] = 0; S[u] = 0; B[u] = 0; }
  unsigned buf[DR > 0 ? DR : 1][5];
  if constexpr (DR > 0) {
#pragma unroll
    for (int i = 0; i < DR; ++i) load_sl(sl, (s + i) * 8 + ly, buf[i]);
  }
  unsigned nxt[5];
  load_sl(sl, (s + DR) * 8 + ly, nxt);

#define SEGRUN(CNT, RB, RE)                                              \
  _Pragma("unroll 1")                                                    \
  for (int R = (RB); R < (RE); ++R) {                                    \
    unsigned cur[5];                                                     \
    _Pragma("unroll")                                                    \
    for (int v = 0; v < 5; ++v) cur[v] = nxt[v];                         \
    load_sl(sl, (s + DR + R + 1) * 8 + ly, nxt); /* prefetch (padded) */ \
    if constexpr (DR > 0) {                                              \
      updoff<DC>(CNT, buf[0], cur);                                      \
      _Pragma("unroll")                                                  \
      for (int i = 0; i < DR - 1; ++i)                                   \
        _Pragma("unroll")                                                \
        for (int v = 0; v < 5; ++v) buf[i][v] = buf[i + 1][v];           \
      _Pragma("unroll")                                                  \
      for (int v = 0; v < 5; ++v) buf[DR > 0 ? DR - 1 : 0][v] = cur[v];  \
    } else {                                                             \
      updoff<DC>(CNT, cur, cur);                                         \
    }                                                                    \
  }

  SEGRUN(A, 0, 4)
  SEGRUN(S, 4, 17 - DR)
  SEGRUN(B, 17 - DR, 21 - DR)
#undef SEGRUN

#pragma unroll
  for (int u = 0; u < 15; ++u) { A[u] += S[u]; B[u] += S[u]; }
  emit2(A, B, Np, v1, v2, pt0, k0, k1);
}

// ---------- Kernel 1: features -> per-tile partials (one 12-wave block per tile) ----------
__global__ __launch_bounds__(768)
void glcm_feat_kernel(const float* __restrict__ x, float* __restrict__ part) {
  __shared__ __align__(16) unsigned sl[79 * 8 * 4];  // pre-sliced masks + 2 pad rows, 10112 B

  const int tid = threadIdx.x;
  const int lane = tid & 63;
  const int wid = tid >> 6;
  const int ty = blockIdx.x;     // 0..15
  const int tx = blockIdx.y;     // 0..7
  const int b = blockIdx.z;
  const int px0 = tx * 64;
  const int py0 = ty * 32;
  const float* xb = x + (size_t)b * 512 * 512;

  const float T1 = 0.5f;
  const float T2 = (float)(85.384 - 53.798);
  const float T3 = 85.384f;
  const float T4 = (float)(85.384 + 53.798);

  // Phase A (fused, once per tile): quantize + ballot -> per-(row,ly) 17-bit level
  // slices as uint4. Lane c covers tile col c; rows striped over the 12 waves.
  // Col/row clamps only affect bits used by invalid windows (masked by v1/v2).
  {
    int gc = py0 + lane; if (gc > 511) gc = 511;
#pragma unroll 1
    for (int r0 = wid; r0 < 77; r0 += 12) {
      int gr = px0 + r0; if (gr > 511) gr = 511;
      float xv = xb[gr * 512 + gc];
      int q = (int)(xv >= T1) + (int)(xv >= T2) + (int)(xv >= T3) + (int)(xv >= T4);
      unsigned long long m1 = __ballot(q == 1);
      unsigned long long m2 = __ballot(q == 2);
      unsigned long long m3 = __ballot(q == 3);
      unsigned long long m4 = __ballot(q == 4);
      if (lane < 8) {
        const int sh4 = 4 * lane;
        unsigned sv0 = (unsigned)(m1 >> sh4) & 0x1FFFFu;
        unsigned sv1 = (unsigned)(m2 >> sh4) & 0x1FFFFu;
        unsigned sv2 = (unsigned)(m3 >> sh4) & 0x1FFFFu;
        unsigned sv3 = (unsigned)(m4 >> sh4) & 0x1FFFFu;
        *(uint4*)(sl + (r0 * 8 + lane) * 4) = make_uint4(sv0, sv1, sv2, sv3);
      }
    }
    // zero pad rows 77-78 (prefetch reads up to row 77)
    if (tid < 16) *(uint4*)(sl + (77 * 8 + tid) * 4) = make_uint4(0, 0, 0, 0);
  }
  __syncthreads();

  // Lane = (lxp, ly): window pair wx1 = tx*16 + 2*lxp (+1); wy = ty*8 + ly.
  const int lxp = lane >> 3, ly = lane & 7;
  const int wx1 = tx * 16 + 2 * lxp;
  const int wy = ty * 8 + ly;
  const bool vy = (wy < 124);
  const bool v1 = (wx1 < 124) && vy;
  const bool v2 = (wx1 + 1 < 124) && vy;
  const int s = 8 * lxp;            // tile-local pixel row of w1
  const int tile = tx * 16 + ty;    // 0..127
  float* pt0 = part + (size_t)b * 68 * 128 + tile;  // channel ch at pt0[ch*128]

  if (wid == 0) {
    // ---- float stats (ch 0-3), phases A/S/B over 21 rows (verified R8/R10) ----
    int sp = px0 + s; if (sp > 488) sp = 488;
    int c0 = py0 + 4 * ly; if (c0 > 492) c0 = 492;
    const float* fw = xb + (size_t)sp * 512 + c0;
    float sA = 0, qA = 0, sS = 0, qS = 0, sB = 0, qB = 0;
    float mxA = -1e30f, mnA = 1e30f, mxS = -1e30f, mnS = 1e30f, mxB = -1e30f, mnB = 1e30f;
#pragma unroll 1
    for (int r = 0; r < 21; ++r) {
      const float* p = fw + r * 512;
      const float4* p4 = (const float4*)p;
      float rs = 0, rq = 0, rmx = -1e30f, rmn = 1e30f;
#pragma unroll
      for (int w = 0; w < 4; ++w) {
        float4 f = p4[w];
        rs += f.x; rq = fmaf(f.x, f.x, rq); rmx = fmaxf(rmx, f.x); rmn = fminf(rmn, f.x);
        rs += f.y; rq = fmaf(f.y, f.y, rq); rmx = fmaxf(rmx, f.y); rmn = fminf(rmn, f.y);
        rs += f.z; rq = fmaf(f.z, f.z, rq); rmx = fmaxf(rmx, f.z); rmn = fminf(rmn, f.z);
        rs += f.w; rq = fmaf(f.w, f.w, rq); rmx = fmaxf(rmx, f.w); rmn = fminf(rmn, f.w);
      }
      float t = p[16];
      rs += t; rq = fmaf(t, t, rq); rmx = fmaxf(rmx, t); rmn = fminf(rmn, t);
      if (r < 4)       { sA += rs; qA += rq; mxA = fmaxf(mxA, rmx); mnA = fminf(mnA, rmn); }
      else if (r < 17) { sS += rs; qS += rq; mxS = fmaxf(mxS, rmx); mnS = fminf(mnS, rmn); }
      else             { sB += rs; qB += rq; mxB = fmaxf(mxB, rmx); mnB = fminf(mnB, rmn); }
    }
    float ch[4][2];
#pragma unroll
    for (int w = 0; w < 2; ++w) {
      float sum = w ? (sS + sB) : (sA + sS);
      float ssq = w ? (qS + qB) : (qA + qS);
      float mx = w ? fmaxf(mxS, mxB) : fmaxf(mxA, mxS);
      float mn = w ? fminf(mnS, mnB) : fminf(mnA, mnS);
      float mean = sum * (1.0f / 289.0f);
      float var = fmaxf(ssq * (1.0f / 289.0f) - mean * mean, 0.0f);
      float fm = mean / G_MEAN_F;
      ch[0][w] = fm;
      ch[1][w] = sqrtf(var) / G_STD_F;
      ch[2][w] = (mx - fm) / G_STD_F;
      ch[3][w] = (fm - mn) / G_STD_F;
    }
#pragma unroll
    for (int c = 0; c < 4; ++c) {
      float f = (v1 ? ch[c][0] : 0.0f) + (v2 ? ch[c][1] : 0.0f);
      f = wred(f);
      if (lane == 0) pt0[c * 128] = f * (1.0f / 15376.0f);
    }
  } else if (wid == 1) {
    // ---- value histogram (ch 4-7) from slice popcounts, phases A/S/B (verified) ----
    unsigned hA[4] = {0,0,0,0}, hS[4] = {0,0,0,0}, hB[4] = {0,0,0,0};
#pragma unroll 1
    for (int R = 0; R < 21; ++R) {
      const uint4 q = *(const uint4*)(sl + ((s + R) * 8 + ly) * 4);
      unsigned* h = (R < 4) ? hA : (R < 17) ? hS : hB;
      h[0] += __popc(q.x); h[1] += __popc(q.y); h[2] += __popc(q.z); h[3] += __popc(q.w);
    }
    float ch[4][2];
#pragma unroll
    for (int w = 0; w < 2; ++w) {
      unsigned t1 = w ? (hS[0] + hB[0]) : (hA[0] + hS[0]);
      unsigned t2 = w ? (hS[1] + hB[1]) : (hA[1] + hS[1]);
      unsigned t3 = w ? (hS[2] + hB[2]) : (hA[2] + hS[2]);
      unsigned t4 = w ? (hS[3] + hB[3]) : (hA[3] + hS[3]);
      unsigned tot = t1 + t2 + t3 + t4;
      float ti = (tot > 0) ? 1.0f / (float)tot : 0.0f;
      ch[0][w] = (float)t1 * ti;
      ch[1][w] = (float)t2 * ti;
      ch[2][w] = (float)t3 * ti;
      ch[3][w] = (float)t4 * ti;
    }
#pragma unroll
    for (int c = 0; c < 4; ++c) {
      float f = (v1 ? ch[c][0] : 0.0f) + (v2 ? ch[c][1] : 0.0f);
      f = wred(f);
      if (lane == 0) pt0[(4 + c) * 128] = f * (1.0f / 15376.0f);
    }
  } else if (wid == 2) {
    glcm2<0, 1>(sl, s, ly, v1, v2, 272.0f, pt0, 0, -1);
  } else if (wid == 3) {
    glcm2<1, 0>(sl, s, ly, v1, v2, 272.0f, pt0, 2, -1);
  } else if (wid == 4) {
    glcm2<0, 2>(sl, s, ly, v1, v2, 255.0f, pt0, 4, -1);
  } else if (wid == 5) {
    glcm2<1, 1>(sl, s, ly, v1, v2, 256.0f, pt0, 1, 5);
  } else if (wid == 6) {
    glcm2<0, 4>(sl, s, ly, v1, v2, 221.0f, pt0, 8, -1);
  } else if (wid == 7) {
    glcm2<1, -1>(sl, s, ly, v1, v2, 256.0f, pt0, 3, 7);
  } else if (wid == 8) {
    glcm2<2, 0>(sl, s, ly, v1, v2, 255.0f, pt0, 6, -1);
  } else if (wid == 9) {
    glcm2<3, 3>(sl, s, ly, v1, v2, 196.0f, pt0, 9, -1);
  } else if (wid == 10) {
    glcm2<4, 0>(sl, s, ly, v1, v2, 221.0f, pt0, 10, -1);
  } else {
    glcm2<3, -3>(sl, s, ly, v1, v2, 196.0f, pt0, 11, -1);
  }
}

// ---------- Kernel 2: reduce 128 tile-partials per (batch,channel) ----------
__global__ __launch_bounds__(64)
void reduce_kernel(const float* __restrict__ part, float* __restrict__ out) {
  const int ch = blockIdx.x;
  const int b = blockIdx.y;
  const int lane = threadIdx.x;
  const float2* p = (const float2*)(part + ((size_t)b * 68 + ch) * 128);
  float2 f = p[lane];
  float v = f.x + f.y;
  v = wred(v);
  if (lane == 0) out[b * 68 + ch] = v;
}

extern "C" void kernel_launch(void* const* d_in, const int* in_sizes, int n_in,
                              void* d_out, int out_size, void* d_ws, size_t ws_size,
                              hipStream_t stream)
{
  const float* x = (const float*)d_in[0];
  float* out = (float*)d_out;
  float* part = (float*)d_ws;   // 278 KB

  glcm_feat_kernel<<<dim3(16, 8, 8), dim3(768), 0, stream>>>(x, part);
  reduce_kernel<<<dim3(68, 8), dim3(64), 0, stream>>>(part, out);
}

// Round 13
// 108.882 us; speedup vs baseline: 1.1098x; 1.1098x over previous
//
#include <hip/hip_runtime.h>

// 8 x 512 x 512 f32 -> 17x17 windows @ stride 4 -> 124x124 windows/batch -> (8,68) means.
// R13 = exact R10 (measured best: 109.7 us total, feature kernel 51 us @ 73% VALUBusy).
// Pipeline: mask precompute -> fat-block feature -> reduce (unique-slot partials, no
// global atomics). R11 (unroll-2, 11-wave) and R12 (fused ballot phase A) both regressed;
// R10 is the verified local optimum.
// Feature kernel: one 768-thr (12-wave) block per 16x8-window tile; lane = 2 vertically-
// adjacent windows via phase counters A/S/B (w1=A+S, w2=S+B); LDS pre-sliced per-(row,ly)
// 17-bit level masks as uint4 (1 ds_read_b128/row); SEGRUN unroll-1 with row prefetch.
// Off-diag bins: disjoint union -> single popc.
// Wave roles (wid): 0 stats ch0-3 | 1 hist ch4-7 | 2:(0,1)k0 3:(1,0)k2 4:(0,2)k4
//   5:(1,1)k1,k5 6:(0,4)k8 7:(1,-1)k3,k7 8:(2,0)k6 9:(3,3)k9 10:(4,0)k10 11:(3,-3)k11
// ws: u64 mg[8][512][9][4] (1.18 MB) then float part[8][68][128] (278 KB).

#define G_MEAN_F 85.384f
#define G_STD_F  53.798f
#define MASK_WS_BYTES (8u * 512u * 36u * 8u)

__device__ constexpr int LO15[15] = {0,0,0,0,0,1,1,1,1,2,2,2,3,3,4};
__device__ constexpr int HI15[15] = {0,1,2,3,4,1,2,3,4,2,3,4,3,4,4};

__device__ __forceinline__ float wred(float v) {
#pragma unroll
  for (int m = 32; m; m >>= 1) v += __shfl_xor(v, m, 64);
  return v;
}

// Load pre-sliced levels 1-4 for slice index (row*8+ly); level 0 by complement.
__device__ __forceinline__ void load_sl(const unsigned* sl, int idx, unsigned m[5]) {
  const uint4 q = *(const uint4*)(sl + idx * 4);
  m[1] = q.x; m[2] = q.y; m[3] = q.z; m[4] = q.w;
  m[0] = 0x1FFFFu & ~(m[1] | m[2] | m[3] | m[4]);
}

// cnt[u] += popc over 15 unordered bins; off-diag sets disjoint -> popc of the union.
template<int DC>
__device__ __forceinline__ void updoff(unsigned* cnt, const unsigned a[5], const unsigned b[5]) {
  unsigned as[5], bs[5];
#pragma unroll
  for (int v = 0; v < 5; ++v) {
    as[v] = (DC < 0) ? (a[v] >> (-DC)) : a[v];
    bs[v] = (DC > 0) ? (b[v] >> DC) : b[v];
  }
#pragma unroll
  for (int u = 0; u < 15; ++u) {
    const int i = LO15[u], j = HI15[u];
    unsigned t = as[i] & bs[j];
    if (i != j) t |= as[j] & bs[i];
    cnt[u] += __popc(t);
  }
}

// GLCM features from symmetric-unordered pair counts (math verified R1-R12).
__device__ __forceinline__ void feat5(const unsigned* cnt, float Np,
                                      float& con, float& hom, float& ene,
                                      float& corr, float& ent) {
  const float invN = 1.0f / Np;
  const float inv2N = 0.5f / Np;
  con = 0.0f; hom = 0.0f; ent = 0.0f;
  float eac = 0.0f;
  float P[5] = {0, 0, 0, 0, 0};
#pragma unroll
  for (int u = 0; u < 15; ++u) {
    const int lo = LO15[u], hi = HI15[u];
    const float m = (float)cnt[u];
    const float d2 = (float)((hi - lo) * (hi - lo));
    con += m * d2;
    hom += m * (1.0f / (1.0f + d2));
    if (lo == hi) {
      eac += m * m;
      P[lo] += 2.0f * m;
      float g = m * invN;
      ent -= g * __log2f(g + 1e-8f);
    } else {
      eac += 0.5f * m * m;
      P[lo] += m; P[hi] += m;
      float g = m * inv2N;
      ent -= 2.0f * g * __log2f(g + 1e-8f);
    }
  }
  con *= invN;
  hom *= invN;
  ene = sqrtf(eac) * invN;
  float mu = 0.0f;
#pragma unroll
  for (int i = 0; i < 5; ++i) { P[i] *= inv2N; mu += (float)i * P[i]; }
  float s2 = 0.0f;
#pragma unroll
  for (int i = 0; i < 5; ++i) { float d = (float)i - mu; s2 = fmaf(P[i] * d, d, s2); }
  float denom = s2;
  float cov = 0.0f;
#pragma unroll
  for (int u = 0; u < 15; ++u)
    cov += ((float)cnt[u] * invN) * ((float)LO15[u] - mu) * ((float)HI15[u] - mu);
  corr = (denom < 1e-15f) ? 1.0f : cov / fmaxf(denom, 1e-30f);
}

// Emit both packed windows' features (summed, validity-masked) to unique partial slots.
__device__ __forceinline__ void emit2(const unsigned c1[15], const unsigned c2[15], float Np,
                                      bool v1, bool v2, float* pt0, int k0, int k1) {
  float con1, hom1, ene1, cor1, ent1, con2, hom2, ene2, cor2, ent2;
  feat5(c1, Np, con1, hom1, ene1, cor1, ent1);
  feat5(c2, Np, con2, hom2, ene2, cor2, ent2);
  if (!v1) { con1 = 0; hom1 = 0; ene1 = 0; cor1 = 0; ent1 = 0; }
  if (!v2) { con2 = 0; hom2 = 0; ene2 = 0; cor2 = 0; ent2 = 0; }
  float con = wred(con1 + con2), hom = wred(hom1 + hom2), ene = wred(ene1 + ene2);
  float cor = wred(cor1 + cor2), ent = wred(ent1 + ent2);
  if ((threadIdx.x & 63) == 0) {
    const float s = 1.0f / 15376.0f;
    pt0[(8 + k0) * 128] = con * s;
    pt0[(20 + k0) * 128] = hom * s;
    pt0[(32 + k0) * 128] = ene * s;
    pt0[(44 + k0) * 128] = cor * s;
    pt0[(56 + k0) * 128] = ent * s;
    if (k1 >= 0) {
      pt0[(8 + k1) * 128] = con * s;
      pt0[(20 + k1) * 128] = hom * s;
      pt0[(32 + k1) * 128] = ene * s;
      pt0[(44 + k1) * 128] = cor * s;
      pt0[(56 + k1) * 128] = ent * s;
    }
  }
}

// One offset over 2 vertically-adjacent windows. Phases: A rows R<4 (w1 only),
// S rows [4,17-DR) (shared), B rows [17-DR,21-DR) (w2 only). Each LDS row loaded ONCE;
// next row prefetched before the current row's AND/POPC body (covers ds_read latency).
template<int DR, int DC>
__device__ void glcm2(const unsigned* sl, int s, int ly, bool v1, bool v2,
                      float Np, float* pt0, int k0, int k1) {
  unsigned A[15], S[15], B[15];
#pragma unroll
  for (int u = 0; u < 15; ++u) { A[u] = 0; S[u] = 0; B[u] = 0; }
  unsigned buf[DR > 0 ? DR : 1][5];
  if constexpr (DR > 0) {
#pragma unroll
    for (int i = 0; i < DR; ++i) load_sl(sl, (s + i) * 8 + ly, buf[i]);
  }
  unsigned nxt[5];
  load_sl(sl, (s + DR) * 8 + ly, nxt);

#define SEGRUN(CNT, RB, RE)                                              \
  _Pragma("unroll 1")                                                    \
  for (int R = (RB); R < (RE); ++R) {                                    \
    unsigned cur[5];                                                     \
    _Pragma("unroll")                                                    \
    for (int v = 0; v < 5; ++v) cur[v] = nxt[v];                         \
    load_sl(sl, (s + DR + R + 1) * 8 + ly, nxt); /* prefetch (padded) */ \
    if constexpr (DR > 0) {                                              \
      updoff<DC>(CNT, buf[0], cur);                                      \
      _Pragma("unroll")                                                  \
      for (int i = 0; i < DR - 1; ++i)                                   \
        _Pragma("unroll")                                                \
        for (int v = 0; v < 5; ++v) buf[i][v] = buf[i + 1][v];           \
      _Pragma("unroll")                                                  \
      for (int v = 0; v < 5; ++v) buf[DR > 0 ? DR - 1 : 0][v] = cur[v];  \
    } else {                                                             \
      updoff<DC>(CNT, cur, cur);                                         \
    }                                                                    \
  }

  SEGRUN(A, 0, 4)
  SEGRUN(S, 4, 17 - DR)
  SEGRUN(B, 17 - DR, 21 - DR)
#undef SEGRUN

#pragma unroll
  for (int u = 0; u < 15; ++u) { A[u] += S[u]; B[u] += S[u]; }
  emit2(A, B, Np, v1, v2, pt0, k0, k1);
}

// ---------- Kernel 1: whole-image mask precompute (verified R5-R10) ----------
__global__ __launch_bounds__(64)
void mask_build_kernel(const float* __restrict__ x, unsigned long long* __restrict__ mg) {
  const int lane = threadIdx.x;
  const int r = blockIdx.x;
  const int b = blockIdx.y;
  const float* xr = x + ((size_t)b * 512 + r) * 512;
  unsigned long long* mr = mg + ((size_t)b * 512 + r) * 36;

  const float T1 = 0.5f;
  const float T2 = (float)(85.384 - 53.798);
  const float T3 = 85.384f;
  const float T4 = (float)(85.384 + 53.798);

#pragma unroll 1
  for (int seg = 0; seg < 8; ++seg) {
    float xv = xr[seg * 64 + lane];
    int q = (int)(xv >= T1) + (int)(xv >= T2) + (int)(xv >= T3) + (int)(xv >= T4);
    unsigned long long b1 = __ballot(q == 1);
    unsigned long long b2 = __ballot(q == 2);
    unsigned long long b3 = __ballot(q == 3);
    unsigned long long b4 = __ballot(q == 4);
    if (lane < 4) {
      unsigned long long bv = (lane == 0) ? b1 : (lane == 1) ? b2 : (lane == 2) ? b3 : b4;
      mr[seg * 4 + lane] = bv;
    }
  }
  if (lane < 4) mr[32 + lane] = 0;  // seg 8 pad (cols >= 512 read as level 0)
}

// ---------- Kernel 2: features -> per-tile partials (one 12-wave block per tile) ----------
__global__ __launch_bounds__(768)
void glcm_feat_kernel(const float* __restrict__ x,
                      const unsigned long long* __restrict__ mg,
                      float* __restrict__ part) {
  __shared__ __align__(16) unsigned sl[79 * 8 * 4];  // pre-sliced masks + 2 pad rows, 10112 B

  const int tid = threadIdx.x;
  const int lane = tid & 63;
  const int wid = tid >> 6;
  const int ty = blockIdx.x;     // 0..15
  const int tx = blockIdx.y;     // 0..7
  const int b = blockIdx.z;
  const int px0 = tx * 64;
  const int py0 = ty * 32;
  const float* xb = x + (size_t)b * 512 * 512;

  // Phase A (once per tile): per-(row,ly) 17-bit level slices (levels 1-4) as uint4.
  const int s0 = py0 >> 6;
  const int sh = py0 & 63;  // 0 or 32
  const unsigned long long* mgb = mg + (size_t)b * 512 * 36 + s0 * 4;
#pragma unroll 1
  for (int t = tid; t < 79 * 8; t += 768) {
    const int row = t >> 3, ly = t & 7;
    unsigned sv[4] = {0, 0, 0, 0};
    if (row < 77) {
      int gr = px0 + row; if (gr > 511) gr = 511;
      const unsigned long long* p = mgb + (size_t)gr * 36;
#pragma unroll
      for (int lev = 0; lev < 4; ++lev) {
        unsigned long long cmb = p[lev];
        if (sh) cmb = (cmb >> 32) | (p[4 + lev] << 32);
        sv[lev] = (unsigned)(cmb >> (4 * ly)) & 0x1FFFFu;
      }
    }
    *(uint4*)(sl + t * 4) = make_uint4(sv[0], sv[1], sv[2], sv[3]);
  }
  __syncthreads();

  // Lane = (lxp, ly): window pair wx1 = tx*16 + 2*lxp (+1); wy = ty*8 + ly.
  const int lxp = lane >> 3, ly = lane & 7;
  const int wx1 = tx * 16 + 2 * lxp;
  const int wy = ty * 8 + ly;
  const bool vy = (wy < 124);
  const bool v1 = (wx1 < 124) && vy;
  const bool v2 = (wx1 + 1 < 124) && vy;
  const int s = 8 * lxp;            // tile-local pixel row of w1
  const int tile = tx * 16 + ty;    // 0..127
  float* pt0 = part + (size_t)b * 68 * 128 + tile;  // channel ch at pt0[ch*128]

  if (wid == 0) {
    // ---- float stats (ch 0-3), phases A/S/B over 21 rows (verified R8) ----
    int sp = px0 + s; if (sp > 488) sp = 488;
    int c0 = py0 + 4 * ly; if (c0 > 492) c0 = 492;
    const float* fw = xb + (size_t)sp * 512 + c0;
    float sA = 0, qA = 0, sS = 0, qS = 0, sB = 0, qB = 0;
    float mxA = -1e30f, mnA = 1e30f, mxS = -1e30f, mnS = 1e30f, mxB = -1e30f, mnB = 1e30f;
#pragma unroll 1
    for (int r = 0; r < 21; ++r) {
      const float* p = fw + r * 512;
      const float4* p4 = (const float4*)p;
      float rs = 0, rq = 0, rmx = -1e30f, rmn = 1e30f;
#pragma unroll
      for (int w = 0; w < 4; ++w) {
        float4 f = p4[w];
        rs += f.x; rq = fmaf(f.x, f.x, rq); rmx = fmaxf(rmx, f.x); rmn = fminf(rmn, f.x);
        rs += f.y; rq = fmaf(f.y, f.y, rq); rmx = fmaxf(rmx, f.y); rmn = fminf(rmn, f.y);
        rs += f.z; rq = fmaf(f.z, f.z, rq); rmx = fmaxf(rmx, f.z); rmn = fminf(rmn, f.z);
        rs += f.w; rq = fmaf(f.w, f.w, rq); rmx = fmaxf(rmx, f.w); rmn = fminf(rmn, f.w);
      }
      float t = p[16];
      rs += t; rq = fmaf(t, t, rq); rmx = fmaxf(rmx, t); rmn = fminf(rmn, t);
      if (r < 4)       { sA += rs; qA += rq; mxA = fmaxf(mxA, rmx); mnA = fminf(mnA, rmn); }
      else if (r < 17) { sS += rs; qS += rq; mxS = fmaxf(mxS, rmx); mnS = fminf(mnS, rmn); }
      else             { sB += rs; qB += rq; mxB = fmaxf(mxB, rmx); mnB = fminf(mnB, rmn); }
    }
    float ch[4][2];
#pragma unroll
    for (int w = 0; w < 2; ++w) {
      float sum = w ? (sS + sB) : (sA + sS);
      float ssq = w ? (qS + qB) : (qA + qS);
      float mx = w ? fmaxf(mxS, mxB) : fmaxf(mxA, mxS);
      float mn = w ? fminf(mnS, mnB) : fminf(mnA, mnS);
      float mean = sum * (1.0f / 289.0f);
      float var = fmaxf(ssq * (1.0f / 289.0f) - mean * mean, 0.0f);
      float fm = mean / G_MEAN_F;
      ch[0][w] = fm;
      ch[1][w] = sqrtf(var) / G_STD_F;
      ch[2][w] = (mx - fm) / G_STD_F;
      ch[3][w] = (fm - mn) / G_STD_F;
    }
#pragma unroll
    for (int c = 0; c < 4; ++c) {
      float f = (v1 ? ch[c][0] : 0.0f) + (v2 ? ch[c][1] : 0.0f);
      f = wred(f);
      if (lane == 0) pt0[c * 128] = f * (1.0f / 15376.0f);
    }
  } else if (wid == 1) {
    // ---- value histogram (ch 4-7) from slice popcounts, phases A/S/B (verified R8) ----
    unsigned hA[4] = {0,0,0,0}, hS[4] = {0,0,0,0}, hB[4] = {0,0,0,0};
#pragma unroll 1
    for (int R = 0; R < 21; ++R) {
      const uint4 q = *(const uint4*)(sl + ((s + R) * 8 + ly) * 4);
      unsigned* h = (R < 4) ? hA : (R < 17) ? hS : hB;
      h[0] += __popc(q.x); h[1] += __popc(q.y); h[2] += __popc(q.z); h[3] += __popc(q.w);
    }
    float ch[4][2];
#pragma unroll
    for (int w = 0; w < 2; ++w) {
      unsigned t1 = w ? (hS[0] + hB[0]) : (hA[0] + hS[0]);
      unsigned t2 = w ? (hS[1] + hB[1]) : (hA[1] + hS[1]);
      unsigned t3 = w ? (hS[2] + hB[2]) : (hA[2] + hS[2]);
      unsigned t4 = w ? (hS[3] + hB[3]) : (hA[3] + hS[3]);
      unsigned tot = t1 + t2 + t3 + t4;
      float ti = (tot > 0) ? 1.0f / (float)tot : 0.0f;
      ch[0][w] = (float)t1 * ti;
      ch[1][w] = (float)t2 * ti;
      ch[2][w] = (float)t3 * ti;
      ch[3][w] = (float)t4 * ti;
    }
#pragma unroll
    for (int c = 0; c < 4; ++c) {
      float f = (v1 ? ch[c][0] : 0.0f) + (v2 ? ch[c][1] : 0.0f);
      f = wred(f);
      if (lane == 0) pt0[(4 + c) * 128] = f * (1.0f / 15376.0f);
    }
  } else if (wid == 2) {
    glcm2<0, 1>(sl, s, ly, v1, v2, 272.0f, pt0, 0, -1);
  } else if (wid == 3) {
    glcm2<1, 0>(sl, s, ly, v1, v2, 272.0f, pt0, 2, -1);
  } else if (wid == 4) {
    glcm2<0, 2>(sl, s, ly, v1, v2, 255.0f, pt0, 4, -1);
  } else if (wid == 5) {
    glcm2<1, 1>(sl, s, ly, v1, v2, 256.0f, pt0, 1, 5);
  } else if (wid == 6) {
    glcm2<0, 4>(sl, s, ly, v1, v2, 221.0f, pt0, 8, -1);
  } else if (wid == 7) {
    glcm2<1, -1>(sl, s, ly, v1, v2, 256.0f, pt0, 3, 7);
  } else if (wid == 8) {
    glcm2<2, 0>(sl, s, ly, v1, v2, 255.0f, pt0, 6, -1);
  } else if (wid == 9) {
    glcm2<3, 3>(sl, s, ly, v1, v2, 196.0f, pt0, 9, -1);
  } else if (wid == 10) {
    glcm2<4, 0>(sl, s, ly, v1, v2, 221.0f, pt0, 10, -1);
  } else {
    glcm2<3, -3>(sl, s, ly, v1, v2, 196.0f, pt0, 11, -1);
  }
}

// ---------- Kernel 3: reduce 128 tile-partials per (batch,channel) ----------
__global__ __launch_bounds__(64)
void reduce_kernel(const float* __restrict__ part, float* __restrict__ out) {
  const int ch = blockIdx.x;
  const int b = blockIdx.y;
  const int lane = threadIdx.x;
  const float2* p = (const float2*)(part + ((size_t)b * 68 + ch) * 128);
  float2 f = p[lane];
  float v = f.x + f.y;
  v = wred(v);
  if (lane == 0) out[b * 68 + ch] = v;
}

extern "C" void kernel_launch(void* const* d_in, const int* in_sizes, int n_in,
                              void* d_out, int out_size, void* d_ws, size_t ws_size,
                              hipStream_t stream)
{
  const float* x = (const float*)d_in[0];
  float* out = (float*)d_out;
  unsigned long long* mg = (unsigned long long*)d_ws;         // 1.18 MB
  float* part = (float*)((char*)d_ws + MASK_WS_BYTES);        // 278 KB

  mask_build_kernel<<<dim3(512, 8), dim3(64), 0, stream>>>(x, mg);
  glcm_feat_kernel<<<dim3(16, 8, 8), dim3(768), 0, stream>>>(x, mg, part);
  reduce_kernel<<<dim3(68, 8), dim3(64), 0, stream>>>(part, out);
}